// Round 3
// baseline (737.236 us; speedup 1.0000x reference)
//
#include <hip/hip_runtime.h>
#include <hip/hip_bf16.h>

// EdgeBlock: out[e] = relu(concat(edge[e], node[recv[e]], node[send[e]], g) @ W1 + b1) @ W2 + b2
// Round 3: latency-hiding pipeline.
//  - grid-stride blocks, each wave owns 16 edges/tile, 2-deep ping-pong register stage
//  - indices prefetched 2 tiles ahead, gathers 1 tile ahead (overlap with GEMMs)
//  - node_feats pre-converted to bf16 in ws: gathers are direct MFMA fragments
//  - global-attr quarter of layer 1 prefolded into acc init (K=192)

typedef __bf16 bf16x8 __attribute__((ext_vector_type(8)));
typedef float f32x4 __attribute__((ext_vector_type(4)));

#define K1 192
#define GRID_MAIN 1536

// ws layout:
//   [0, 49152)            W1T bf16 [128][192]
//   [49152, 65536)        W2T bf16 [64][128]
//   [65536, 66048)        g1  f32  [128]
//   [66560, 66560+2*N*64) node_bf16 [N_NODES][64]   (only if ws_size allows)
#define WS_NODEBF_OFF 66560

__global__ void prep_kernel(const float* __restrict__ W1, const float* __restrict__ b1,
                            const float* __restrict__ W2, const float* __restrict__ gattr,
                            __bf16* __restrict__ W1T, __bf16* __restrict__ W2T,
                            float* __restrict__ g1) {
    int tid = blockIdx.x * blockDim.x + threadIdx.x;
    if (tid < 128 * 192) {
        int n = tid / 192, k = tid % 192;
        W1T[n * 192 + k] = (__bf16)W1[k * 128 + n];
    } else if (tid < 128 * 192 + 64 * 128) {
        int t = tid - 128 * 192;
        int n = t / 128, k = t % 128;
        W2T[n * 128 + k] = (__bf16)W2[k * 64 + n];
    } else if (tid < 128 * 192 + 64 * 128 + 128) {
        int n = tid - (128 * 192 + 64 * 128);
        float acc = b1[n];
        for (int j = 0; j < 64; ++j) acc += gattr[j] * W1[(192 + j) * 128 + n];
        g1[n] = acc;
    }
}

__global__ __launch_bounds__(256) void node_conv_kernel(const float* __restrict__ nf,
                                                        __bf16* __restrict__ nb, int n8) {
    int t = blockIdx.x * blockDim.x + threadIdx.x;  // one thread per 8 floats
    if (t < n8) {
        f32x4 a = *(const f32x4*)(nf + (long)t * 8);
        f32x4 b = *(const f32x4*)(nf + (long)t * 8 + 4);
        bf16x8 o;
#pragma unroll
        for (int j = 0; j < 4; ++j) { o[j] = (__bf16)a[j]; o[4 + j] = (__bf16)b[j]; }
        *(bf16x8*)(nb + (long)t * 8) = o;
    }
}

__device__ __forceinline__ f32x4 mk4(float v) {
    f32x4 r; r[0] = v; r[1] = v; r[2] = v; r[3] = v; return r;
}

template<bool NB>
__global__ __launch_bounds__(256, 3) void edge_mlp_kernel(
    const float* __restrict__ edge_feats, const float* __restrict__ node_feats,
    const __bf16* __restrict__ node_bf,
    const int* __restrict__ senders, const int* __restrict__ receivers,
    const __bf16* __restrict__ W1T, const __bf16* __restrict__ W2T,
    const float* __restrict__ g1, const float* __restrict__ b2,
    float* __restrict__ out, int E, int numTiles)
{
    __shared__ __bf16 h_lds[4][16][136];

    const int lane = threadIdx.x & 63;
    const int w    = threadIdx.x >> 6;
    const int c    = lane & 15;
    const int g    = lane >> 4;
    const int G    = gridDim.x;

    // loop-invariant hoists
    float gv[8], b2v[4];
#pragma unroll
    for (int nt = 0; nt < 8; ++nt) gv[nt] = g1[nt * 16 + c];
#pragma unroll
    for (int nt = 0; nt < 4; ++nt) b2v[nt] = b2[nt * 16 + c];

    const int numMine = (numTiles - blockIdx.x + G - 1) / G;

    auto tile_row = [&](int i) {
        int bt = blockIdx.x + i * G;
        int row = bt * 64 + w * 16 + c;
        return row > E - 1 ? E - 1 : row;
    };

    // prefetch: issue 12B-gather set for a tile into stage regs
    auto gath = [&](f32x4 (&est)[4], bf16x8 (&nst)[4], f32x4 (&nstf)[8],
                    int row, int rR, int rS) {
        const float* pe = edge_feats + (long)row * 64;
#pragma unroll
        for (int ks = 0; ks < 2; ++ks) {
            est[2 * ks]     = *(const f32x4*)(pe + ks * 32 + g * 8);
            est[2 * ks + 1] = *(const f32x4*)(pe + ks * 32 + g * 8 + 4);
        }
        if constexpr (NB) {
            const __bf16* pr = node_bf + (long)rR * 64;
            const __bf16* ps = node_bf + (long)rS * 64;
            nst[0] = *(const bf16x8*)(pr + g * 8);
            nst[1] = *(const bf16x8*)(pr + 32 + g * 8);
            nst[2] = *(const bf16x8*)(ps + g * 8);
            nst[3] = *(const bf16x8*)(ps + 32 + g * 8);
        } else {
            const float* pr = node_feats + (long)rR * 64;
            const float* ps = node_feats + (long)rS * 64;
#pragma unroll
            for (int ks = 0; ks < 2; ++ks) {
                nstf[2 * ks]         = *(const f32x4*)(pr + ks * 32 + g * 8);
                nstf[2 * ks + 1]     = *(const f32x4*)(pr + ks * 32 + g * 8 + 4);
                nstf[4 + 2 * ks]     = *(const f32x4*)(ps + ks * 32 + g * 8);
                nstf[4 + 2 * ks + 1] = *(const f32x4*)(ps + ks * 32 + g * 8 + 4);
            }
        }
    };

    auto cvt8 = [&](const f32x4& lo, const f32x4& hi) {
        bf16x8 t;
#pragma unroll
        for (int j = 0; j < 4; ++j) { t[j] = (__bf16)lo[j]; t[4 + j] = (__bf16)hi[j]; }
        return t;
    };

    auto do_tile = [&](f32x4 (&est)[4], bf16x8 (&nst)[4], f32x4 (&nstf)[8], int i) {
        bf16x8 a[6];
        a[0] = cvt8(est[0], est[1]);
        a[1] = cvt8(est[2], est[3]);
        if constexpr (NB) {
            a[2] = nst[0]; a[3] = nst[1]; a[4] = nst[2]; a[5] = nst[3];
        } else {
            a[2] = cvt8(nstf[0], nstf[1]); a[3] = cvt8(nstf[2], nstf[3]);
            a[4] = cvt8(nstf[4], nstf[5]); a[5] = cvt8(nstf[6], nstf[7]);
        }

        f32x4 acc[8];
#pragma unroll
        for (int nt = 0; nt < 8; ++nt) acc[nt] = mk4(gv[nt]);
#pragma unroll
        for (int nt = 0; nt < 8; ++nt)
#pragma unroll
            for (int ks = 0; ks < 6; ++ks) {
                bf16x8 b = *(const bf16x8*)(W1T + (nt * 16 + c) * K1 + ks * 32 + g * 8);
                acc[nt] = __builtin_amdgcn_mfma_f32_16x16x32_bf16(a[ks], b, acc[nt], 0, 0, 0);
            }

#pragma unroll
        for (int nt = 0; nt < 8; ++nt)
#pragma unroll
            for (int r = 0; r < 4; ++r) {
                float v = acc[nt][r];
                v = v > 0.f ? v : 0.f;
                h_lds[w][g * 4 + r][nt * 16 + c] = (__bf16)v;
            }
        asm volatile("s_waitcnt lgkmcnt(0)" ::: "memory");
        __builtin_amdgcn_sched_barrier(0);

        f32x4 acc2[4];
#pragma unroll
        for (int nt = 0; nt < 4; ++nt) acc2[nt] = mk4(b2v[nt]);
#pragma unroll
        for (int ks = 0; ks < 4; ++ks) {
            bf16x8 a2 = *(const bf16x8*)&h_lds[w][c][ks * 32 + g * 8];
#pragma unroll
            for (int nt = 0; nt < 4; ++nt) {
                bf16x8 b = *(const bf16x8*)(W2T + (nt * 16 + c) * 128 + ks * 32 + g * 8);
                acc2[nt] = __builtin_amdgcn_mfma_f32_16x16x32_bf16(a2, b, acc2[nt], 0, 0, 0);
            }
        }

        const int sbase = (blockIdx.x + i * G) * 64 + w * 16 + g * 4;
#pragma unroll
        for (int nt = 0; nt < 4; ++nt)
#pragma unroll
            for (int r = 0; r < 4; ++r) {
                if (sbase + r < E)
                    out[(long)(sbase + r) * 64 + nt * 16 + c] = acc2[nt][r];
            }
    };

    // ---- pipeline ----
    f32x4 estA[4], estB[4], nstfA[8], nstfB[8];
    bf16x8 nstA[4], nstB[4];

    int rowP = tile_row(0);
    int iR = receivers[rowP], iS = senders[rowP];
    gath(estA, nstA, nstfA, rowP, iR, iS);          // gathers tile 0 -> A
    rowP = tile_row(1); iR = receivers[rowP]; iS = senders[rowP];  // idx tile 1

    for (int i = 0; i < numMine; ) {
        gath(estB, nstB, nstfB, rowP, iR, iS);      // gathers tile i+1 -> B
        rowP = tile_row(i + 2); iR = receivers[rowP]; iS = senders[rowP];
        do_tile(estA, nstA, nstfA, i);
        ++i; if (i >= numMine) break;

        gath(estA, nstA, nstfA, rowP, iR, iS);      // gathers tile i+1 -> A
        rowP = tile_row(i + 2); iR = receivers[rowP]; iS = senders[rowP];
        do_tile(estB, nstB, nstfB, i);
        ++i;
    }
}

extern "C" void kernel_launch(void* const* d_in, const int* in_sizes, int n_in,
                              void* d_out, int out_size, void* d_ws, size_t ws_size,
                              hipStream_t stream) {
    const float* edge_feats = (const float*)d_in[0];
    const float* node_feats = (const float*)d_in[1];
    const float* gattr      = (const float*)d_in[2];
    const int*   senders    = (const int*)d_in[3];
    const int*   receivers  = (const int*)d_in[4];
    const float* W1         = (const float*)d_in[5];
    const float* b1         = (const float*)d_in[6];
    const float* W2         = (const float*)d_in[7];
    const float* b2         = (const float*)d_in[8];
    float* out = (float*)d_out;

    const int E = in_sizes[3];        // N_EDGES
    const int N = in_sizes[1] / 64;   // N_NODES (node_feats is N x 64)

    char* ws = (char*)d_ws;
    __bf16* W1T = (__bf16*)ws;
    __bf16* W2T = (__bf16*)(ws + 49152);
    float*  g1  = (float*)(ws + 49152 + 16384);
    __bf16* nodeBF = (__bf16*)(ws + WS_NODEBF_OFF);

    const size_t ws_needed = (size_t)WS_NODEBF_OFF + (size_t)N * 64 * 2;
    const bool useNB = ws_size >= ws_needed;

    int prep_total = 128 * 192 + 64 * 128 + 128;
    prep_kernel<<<(prep_total + 255) / 256, 256, 0, stream>>>(W1, b1, W2, gattr, W1T, W2T, g1);

    if (useNB) {
        int n8 = N * 8;  // threads, 8 floats each
        node_conv_kernel<<<(n8 + 255) / 256, 256, 0, stream>>>(node_feats, nodeBF, n8);
    }

    const int numTiles = (E + 63) / 64;
    int grid = numTiles < GRID_MAIN ? numTiles : GRID_MAIN;
    if (useNB) {
        edge_mlp_kernel<true><<<grid, 256, 0, stream>>>(edge_feats, node_feats, nodeBF,
                                                        senders, receivers, W1T, W2T, g1, b2,
                                                        out, E, numTiles);
    } else {
        edge_mlp_kernel<false><<<grid, 256, 0, stream>>>(edge_feats, node_feats, nodeBF,
                                                         senders, receivers, W1T, W2T, g1, b2,
                                                         out, E, numTiles);
    }
}